// Round 14
// baseline (98.148 us; speedup 1.0000x reference)
//
#include <hip/hip_runtime.h>

// ConvCRF forward, MI355X — round 29: f16 halo + cvt taps (LDS-pipe relief).
// R28 re-established R23 baseline (97.1us harness, ~38.7us kernel).
// Pipe budget with correct units: LDS is ONE pipe per CU (128 B/cy shared by
// all 8 waves); VALU is per-SIMD (4 pipes). Tap loop/CU/iter: 8w x 49 b128 x
// ~12cy ~ 4700cyc LDS vs ~1600cyc VALU per SIMD -> LDS-bound ~3x, VALU has
// headroom. R17's f32 halo spent the scarce pipe to save the abundant one.
// R29: f16x4 sm halo, ds_read_b64 + 4 v_cvt_f32_f16 + 6 v_pk_fma_f32 per tap
// (NOT R18's fma_mix which doubled FMAs). Halves sm tap bytes. Plane stride
// 26 half4-units: bankpair = (26r+c) mod 16 = px mod 16 -> uniform 2-way =
// FREE (m136). Staging/interior = raw f16 u64 copies (R15 style; absmax may
// return to the previously-passing 0.03125).
// Single change vs R28; if wash -> structural floor, revert + declare.
// Carried: LCP4=18 rgb halo, grid (16,16) = 1 block/CU, 10x10 tiles, tag
// epochs + watchdog, early sm0 publish, neighbor-only sync, rgb prefetch
// under M, 2-exp taps, partial bilateral norms, separable spatial norm,
// ring staging, diag fast path, O(19)/entry M prologue, f16 agent-atomic
// exchange.

typedef __attribute__((ext_vector_type(4))) _Float16 half4;
typedef __attribute__((ext_vector_type(2))) _Float16 half2f;
typedef __attribute__((ext_vector_type(4))) float float4v;

#define HH 160
#define WW 160
#define NPIX (HH*WW)
#define NC 19
#define NG 5
#define SPAN 3
#define TR 10
#define TC 10
#define NPXT 100           // pixels per group
#define LR 16              // TR + 2*SPAN
#define LC 16              // TC + 2*SPAN
#define LCP4 18            // rgb halo row stride (float4 units)
#define HSTR4 (LR*LCP4)    // 288
#define LCPH 26            // sm halo row stride (half4 units) — 2-way-free
#define HSTRH (LR*LCPH)    // 416
#define NHALO (LR*LC)      // 256
#define NRING 156          // NHALO - 10*10 interior
#define NBLK 256
#define NTHR 512
#define NACT 500           // active compute threads (5 groups x 100 px)
#define EPSF 1e-20f

// epoch word encoding: hi16 = tag, lo16 = seq (it+1). Any hi16 != tag -> seq 0.
// Tag bytes differ (0x5E vs 0xED) so NO byte-uniform poison can alias it.
#define EPTAG   0x5EED0000u
#define EPMASK  0xFFFF0000u

// bar layout (u32 words): epoch[b] at word 32+b*32 (128B stride); word 0 unused
#define EPW(b) (32 + (b)*32)

// region A (byte offsets in shm):
//   rgbL   : 0 .. 9216          (2 x 288 float4, prologue only)
//   PN     : 9216 .. 13216      (500 float2 partial norms, phase 2a->2b only)
//   smH    : 0 .. 16640         (5 x 416 half4, per-iter sm halo)
//   accF   : 0 .. 24000         (60 x 100 f32, dead-path epilogue)
#define SZ_A    24064
#define PN_OFF  9216
#define OFF_WB  SZ_A                // weights: 25 pairs x 200 words = 20000 B
#define SHM_SZ  (SZ_A + 20000)      // 44,064

__device__ __forceinline__ float fast_rcp(float x) { return __builtin_amdgcn_rcpf(x); }

__device__ __forceinline__ float smx0(float q0, float q1) {
    const float m  = fmaxf(q0, q1);
    const float e0 = __expf(q0 - m);
    const float e1 = __expf(q1 - m);
    return e0 * fast_rcp(e0 + e1);
}

__device__ __forceinline__ unsigned ep_decode(unsigned w) {
    return ((w & EPMASK) == EPTAG) ? (w & 0xFFFFu) : 0u;
}

__global__ void __launch_bounds__(NTHR) crf_kernel(
        const float* __restrict__ u,
        const float* __restrict__ rgb,
        const float* __restrict__ sw,
        const float* __restrict__ bw,
        const float* __restrict__ compat,
        unsigned long long* __restrict__ gsmA,   // ping-pong sm0 fields (f16x4)
        unsigned long long* __restrict__ gsmB,
        unsigned* __restrict__ bar,
        float* __restrict__ out) {
    __shared__ __align__(16) char shm[SHM_SZ];
    __shared__ float Msh[960];                   // 20x48 rows [Ms|Mb|RS|pad]
    __shared__ float rowsum[NC];
    __shared__ int   diagflag;
    float4*   rgbL = (float4*)shm;               // prologue only (region A)
    half4*    smH  = (half4*)shm;                // per-iter sm0 halo, f16 (region A)
    float*    accF = (float*)shm;                // general-path epilogue (region A)
    unsigned* wbW  = (unsigned*)(shm + OFF_WB);
    const uint2* wbP = (const uint2*)(shm + OFF_WB);

    constexpr float WSPC[49] = {
        0.36787944f,0.48567179f,0.57375342f,0.60653066f,0.57375342f,0.48567179f,0.36787944f,
        0.48567179f,0.64118039f,0.75746513f,0.80073740f,0.75746513f,0.64118039f,0.48567179f,
        0.57375342f,0.75746513f,0.89483932f,0.94595947f,0.89483932f,0.75746513f,0.57375342f,
        0.60653066f,0.80073740f,0.94595947f,1.00000000f,0.94595947f,0.80073740f,0.60653066f,
        0.57375342f,0.75746513f,0.89483932f,0.94595947f,0.89483932f,0.75746513f,0.57375342f,
        0.48567179f,0.64118039f,0.75746513f,0.80073740f,0.75746513f,0.64118039f,0.48567179f,
        0.36787944f,0.48567179f,0.57375342f,0.60653066f,0.57375342f,0.48567179f,0.36787944f };

    const int tid = threadIdx.x;
    const bool act = (tid < NACT);
    const int g   = tid / NPXT;                 // 0..4 (5 for idle tail, guarded)
    const int px  = tid - g * NPXT;             // 0..99
    const int r   = px / TC, c = px - r * TC;   // 10x10 tile coords
    const int ti0 = blockIdx.y * TR, tj0 = blockIdx.x * TC;
    const int gp  = (ti0 + r) * WW + (tj0 + c);
    const int ctr4 = (r + SPAN) * LCP4 + (c + SPAN);   // rgb halo center
    const int ctrH = (r + SPAN) * LCPH + (c + SPAN);   // sm halo center
    const int ku  = 4 * g;
    const int bid = blockIdx.y * 16 + blockIdx.x;    // grid (16, 16)

    // neighbor epochs to wait on (pad missing neighbors with own bid)
    int nb[8];
    {
        const int bx = blockIdx.x, by = blockIdx.y;
        int k = 0;
        #pragma unroll
        for (int dy2 = -1; dy2 <= 1; ++dy2)
            #pragma unroll
            for (int dx2 = -1; dx2 <= 1; ++dx2) {
                if (dx2 == 0 && dy2 == 0) continue;
                const int nx = bx + dx2, ny = by + dy2;
                nb[k++] = ((unsigned)nx < 16u && (unsigned)ny < 16u) ? (ny*16 + nx) : bid;
            }
    }

    if (tid == 0) diagflag = 1;

    // ---- earliest possible: own unaries -> sm0 -> publish (iteration 0) ----
    float uv0[4], uv1[4];
    half4 sh;
    if (act) {
        #pragma unroll
        for (int i = 0; i < 4; ++i) {
            const int ch = 4*g + i;
            uv0[i] = (ch < NC) ? u[(size_t)gp * NC + ch] : 0.0f;
            uv1[i] = (ch < NC) ? u[((size_t)NPIX + gp) * NC + ch] : 0.0f;
        }
        #pragma unroll
        for (int i = 0; i < 4; ++i) sh[i] = (_Float16)smx0(uv0[i], uv1[i]);
        unsigned long long u64; __builtin_memcpy(&u64, &sh, 8);
        __hip_atomic_store(&gsmA[g * NPIX + gp], u64,
                           __ATOMIC_RELAXED, __HIP_MEMORY_SCOPE_AGENT);
    }

    if (tid < NC) {
        float rs = 0.0f;
        for (int cb = 0; cb < NC; ++cb) rs += sw[tid*NC + cb] + bw[tid*NC + cb];
        rowsum[tid] = rs;
    }
    __syncthreads();             // drains ALL waves' sm0 publishes (vmcnt 0)
    if (tid == 0)                // epoch visible to neighbors during prologue
        __hip_atomic_store(&bar[EPW(bid)], EPTAG | 1u,
                           __ATOMIC_RELAXED, __HIP_MEMORY_SCOPE_AGENT);

    // ---- rgb halo prefetch: exactly 1 element/thread (2*256 = 512 = NTHR),
    //      issued BEFORE the M compute so the load latency hides under it ----
    float4 rv;
    int rgb_idx;
    {
        const int bb = tid >> 8, pos = tid & 255;
        const int hr = pos >> 4, hc = pos & 15;
        const int yi = ti0 - SPAN + hr, xj = tj0 - SPAN + hc;
        rv = make_float4(0.f, 0.f, 0.f, 0.f);
        if ((unsigned)yi < HH && (unsigned)xj < WW) {
            const float* p = rgb + ((size_t)(bb * NPIX) + yi * WW + xj) * 3;
            rv = make_float4(p[0]*(1.f/160.f), p[1]*(1.f/160.f), p[2]*(1.f/160.f), 1.f);
        }
        rgb_idx = bb * HSTR4 + hr * LCP4 + hc;
    }

    // ---- phase 0: M = [compat@sw | compat@bw | RS] into LDS, O(19)/entry ----
    for (int e = tid; e < 960; e += NTHR) {
        const int k = e / 48, cc2 = e % 48;
        float acc = 0.0f;
        if (k < NC) {
            if (cc2 < NC) {
                for (int j = 0; j < NC; ++j) acc += compat[k*NC + j] * sw[j*NC + cc2];
            } else if (cc2 >= 20 && cc2 < 20 + NC) {
                const int cb = cc2 - 20;
                for (int j = 0; j < NC; ++j) acc += compat[k*NC + j] * bw[j*NC + cb];
            } else if (cc2 == 40) {
                for (int j = 0; j < NC; ++j) acc += compat[k*NC + j] * rowsum[j];
            }
        }
        Msh[e] = acc;
        bool off = false;
        if (k < NC) {
            if (cc2 < NC && cc2 != k && acc != 0.0f) off = true;
            if (cc2 >= 20 && cc2 < 20 + NC && (cc2 - 20) != k && acc != 0.0f) off = true;
        }
        if (off) atomicAnd(&diagflag, 0);
    }

    // ---- phase 1: rgb halo writeback (waits on the prefetch here) ----
    rgbL[rgb_idx] = rv;
    __syncthreads();             // covers Msh + rgbL

    float dsv[4], dbv[4];
    #pragma unroll
    for (int i = 0; i < 4; ++i) {
        dsv[i] = Msh[(ku + i) * 48 + (ku + i)];
        dbv[i] = Msh[(ku + i) * 48 + 20 + (ku + i)];
    }
    const bool isdiag = (diagflag != 0);

    // ---- phase 2a: bilateral weights (tap-subset per group) -> LDS pairs,
    //      spatial exponent folded into the batch exponent (2 exps/tap),
    //      f16-rounded partial norms accumulated on the fly ----
    if (act) {
        const float4 cv0 = rgbL[ctr4];
        const float4 cv1 = rgbL[HSTR4 + ctr4];
        const int tapb = g * 10;
        const int ntap = (g == 4) ? 9 : 10;
        float pn0 = 0.f, pn1 = 0.f;
        for (int i = 0; i < ntap; ++i) {
            const int t = tapb + i;
            const int dx = t / 7 - SPAN, dy = t % 7 - SPAN;
            const int n = ctr4 + dx * LCP4 + dy;
            const float4 nv0 = rgbL[n];
            const float4 nv1 = rgbL[HSTR4 + n];
            const float spc = (float)(dx*dx + dy*dy) * (-1.f/18.f);
            const float dr0 = cv0.x-nv0.x, dg0 = cv0.y-nv0.y, db0 = cv0.z-nv0.z;
            const float dr1 = cv1.x-nv1.x, dg1 = cv1.y-nv1.y, db1 = cv1.z-nv1.z;
            const float d0 = dr0*dr0 + dg0*dg0 + db0*db0;
            const float d1 = dr1*dr1 + dg1*dg1 + db1*db1;
            const float wb0 = nv0.w * __expf(fmaf(d0, -0.5f, spc));
            const float wb1 = nv0.w * __expf(fmaf(d1, -0.5f, spc));
            half2f hw = {(_Float16)wb0, (_Float16)wb1};
            unsigned uw; __builtin_memcpy(&uw, &hw, 4);
            wbW[(t >> 1) * 200 + px * 2 + (t & 1)] = uw;
            pn0 += (float)hw.x; pn1 += (float)hw.y;
        }
        if (g == 4) wbW[24 * 200 + px * 2 + 1] = 0u;
        *(float2*)(shm + PN_OFF + (g * NPXT + px) * 8) = make_float2(pn0, pn1);
    }
    __syncthreads();

    // ---- phase 2b: inverse norms — 5-term partial reduce + separable sn ----
    float snI, bnI0, bnI1;
    if (act) {
        float bn0 = 0.f, bn1 = 0.f;
        #pragma unroll
        for (int g2 = 0; g2 < 5; ++g2) {
            const float2 p = *(const float2*)(shm + PN_OFF + (g2 * NPXT + px) * 8);
            bn0 += p.x; bn1 += p.y;
        }
        const int rg = ti0 + r, cg = tj0 + c;
        float Rr = 5.70645506f, Cc = 5.70645506f;
        Rr -= (rg < 3   ? 0.60653066f : 0.f) + (rg < 2   ? 0.80073740f : 0.f)
            + (rg < 1   ? 0.94595947f : 0.f) + (rg > 156 ? 0.60653066f : 0.f)
            + (rg > 157 ? 0.80073740f : 0.f) + (rg > 158 ? 0.94595947f : 0.f);
        Cc -= (cg < 3   ? 0.60653066f : 0.f) + (cg < 2   ? 0.80073740f : 0.f)
            + (cg < 1   ? 0.94595947f : 0.f) + (cg > 156 ? 0.60653066f : 0.f)
            + (cg > 157 ? 0.80073740f : 0.f) + (cg > 158 ? 0.94595947f : 0.f);
        snI  = fast_rcp(Rr * Cc + EPSF);
        bnI0 = fast_rcp(bn0 + EPSF);
        bnI1 = fast_rcp(bn1 + EPSF);
    }

    for (int it = 0; it < 5; ++it) {
        // drain tail publishes of this iteration (vmcnt 0) + all waves past
        // previous LDS reads (incl. 2b's partial reads) -> region A reusable
        __syncthreads();

        // interior self-write from f16 registers (overlaps tid0's poll)
        if (act) smH[g * HSTRH + ctrH] = sh;

        // ---- neighbor-only epoch sync (tag-encoded, poison-robust) ----
        // Bounded spin: never triggers when all blocks are live; converts a
        // would-be deadlock into a completing-but-wrong run (diagnostic).
        if (tid == 0) {
            const unsigned seq = (unsigned)(it + 1);
            if (it > 0)
                __hip_atomic_store(&bar[EPW(bid)], EPTAG | seq,
                                   __ATOMIC_RELAXED, __HIP_MEMORY_SCOPE_AGENT);
            unsigned mn;
            unsigned spins = 0;
            do {
                mn = 0xFFFFu;
                #pragma unroll
                for (int k = 0; k < 8; ++k) {
                    const unsigned w = __hip_atomic_load(&bar[EPW(nb[k])],
                                                         __ATOMIC_RELAXED, __HIP_MEMORY_SCOPE_AGENT);
                    const unsigned e = ep_decode(w);
                    mn = (e < mn) ? e : mn;
                }
                if (mn < seq) {
                    __builtin_amdgcn_s_sleep(1);
                    if (++spins > (1u << 22)) break;   // watchdog (~0.2s)
                }
            } while (mn < seq);
        }
        __syncthreads();

        // ---- stage: ring from gsm (raw f16 u64 copy) ----
        const unsigned long long* gsrc = ((it & 1) ? gsmB : gsmA);
        #pragma unroll
        for (int k2 = 0; k2 < 2; ++k2) {
            const int e = tid + NTHR * k2;
            if (e < NG * NRING) {
                const int sg = e / NRING, re = e - sg * NRING;
                int hr, hc;
                if (re < 48)        { hr = re >> 4;               hc = re & 15; }
                else if (re < 96)   { hr = 13 + ((re - 48) >> 4); hc = (re - 48) & 15; }
                else                { const int t2 = re - 96; hr = 3 + t2 / 6;
                                      const int s = t2 % 6;   hc = (s < 3) ? s : s + 10; }
                const int yi = ti0 - SPAN + hr, xj = tj0 - SPAN + hc;
                half4 hv = (half4)(_Float16)0.0f;
                if ((unsigned)yi < HH && (unsigned)xj < WW) {
                    const unsigned long long raw =
                        __hip_atomic_load(&gsrc[sg * NPIX + yi * WW + xj],
                                          __ATOMIC_RELAXED, __HIP_MEMORY_SCOPE_AGENT);
                    __builtin_memcpy(&hv, &raw, 8);
                }
                smH[sg * HSTRH + hr * LCPH + hc] = hv;
            }
        }
        __syncthreads();

        // ---- 49 taps as 24 pairs + 1: ds_read_b64 (2-way free) + cvt + pk_fma ----
        float4v sAv = (float4v)0.0f, b0a = (float4v)0.0f, b1a = (float4v)0.0f;
        if (act) {
            const half4* pl = smH + g * HSTRH;
            #pragma unroll
            for (int i = 0; i < 24; ++i) {
                const uint2 wp = wbP[i * 100 + px];
                #pragma unroll
                for (int s = 0; s < 2; ++s) {
                    const int t = 2*i + s;
                    const int dx = t / 7 - SPAN, dy = t % 7 - SPAN;
                    half2f hw; __builtin_memcpy(&hw, s ? &wp.y : &wp.x, 4);
                    const float w0 = (float)hw.x, w1 = (float)hw.y;
                    const half4 v = pl[ctrH + dx*LCPH + dy];
                    const float4v f = {(float)v[0], (float)v[1], (float)v[2], (float)v[3]};
                    sAv += WSPC[t] * f;
                    b0a += w0 * f;
                    b1a += w1 * f;
                }
            }
            {   // tap 48
                const uint2 wp = wbP[24 * 100 + px];
                half2f hw; __builtin_memcpy(&hw, &wp.x, 4);
                const float w0 = (float)hw.x, w1 = (float)hw.y;
                const half4 v = pl[ctrH + SPAN*LCPH + SPAN];
                const float4v f = {(float)v[0], (float)v[1], (float)v[2], (float)v[3]};
                sAv += WSPC[48] * f;
                b0a += w0 * f;
                b1a += w1 * f;
            }
        }

        float q0v[4], q1v[4];
        if (isdiag) {
            if (act) {
                #pragma unroll
                for (int i = 0; i < 4; ++i) {
                    const float sAn = sAv[i] * snI;
                    const float b0n = b0a[i] * bnI0;
                    const float b1x = b1a[i] * bnI1;
                    q0v[i] = uv0[i] - dsv[i]*sAn - dbv[i]*b0n;
                    q1v[i] = uv1[i] - (dsv[i] + dbv[i]) + dsv[i]*sAn + dbv[i]*b1x;
                }
            }
        } else {
            __syncthreads();   // smH dead -> region A becomes accF
            if (act) {
                #pragma unroll
                for (int i = 0; i < 4; ++i) {
                    accF[(4*g + i) * NPXT + px]      = sAv[i] * snI;
                    accF[(20 + 4*g + i) * NPXT + px] = b0a[i] * bnI0;
                    accF[(40 + 4*g + i) * NPXT + px] = b1a[i] * bnI1;
                }
            }
            __syncthreads();
            if (act) {
                float t1[4] = {0,0,0,0}, t2[4] = {0,0,0,0}, t3[4] = {0,0,0,0};
                #pragma unroll
                for (int cc = 0; cc < 20; ++cc) {
                    const float sv  = accF[cc * NPXT + px];
                    const float b0v = accF[(20 + cc) * NPXT + px];
                    const float b1v = accF[(40 + cc) * NPXT + px];
                    #pragma unroll
                    for (int i = 0; i < 4; ++i) {
                        const float* mk = Msh + (ku + i) * 48;
                        t1[i] += mk[cc] * sv;
                        t2[i] += mk[20 + cc] * b0v;
                        t3[i] += mk[20 + cc] * b1v;
                    }
                }
                #pragma unroll
                for (int i = 0; i < 4; ++i) {
                    const float rs = Msh[(ku + i) * 48 + 40];
                    q0v[i] = uv0[i] - t1[i] - t2[i];
                    q1v[i] = uv1[i] - rs + t1[i] + t3[i];
                }
            }
        }

        if (it == 4) {
            if (act) {
                #pragma unroll
                for (int i = 0; i < 4; ++i) {
                    const int ch = 4*g + i;
                    if (ch < NC) {
                        out[(size_t)gp * NC + ch]          = q0v[i];
                        out[((size_t)NPIX + gp) * NC + ch] = q1v[i];
                    }
                }
            }
        } else if (act) {
            // sm for iteration it+1: f16 in regs (interior) + f16 publish (halo)
            #pragma unroll
            for (int i = 0; i < 4; ++i) sh[i] = (_Float16)smx0(q0v[i], q1v[i]);
            unsigned long long u64; __builtin_memcpy(&u64, &sh, 8);
            unsigned long long* gdst = (((it + 1) & 1) ? gsmB : gsmA);
            __hip_atomic_store(&gdst[g * NPIX + gp], u64,
                               __ATOMIC_RELAXED, __HIP_MEMORY_SCOPE_AGENT);
        }
    }
}

extern "C" void kernel_launch(void* const* d_in, const int* in_sizes, int n_in,
                              void* d_out, int out_size, void* d_ws, size_t ws_size,
                              hipStream_t stream) {
    const float* u      = (const float*)d_in[0];
    const float* rgb    = (const float*)d_in[1];
    const float* sw     = (const float*)d_in[2];
    const float* bw     = (const float*)d_in[3];
    const float* compat = (const float*)d_in[4];
    float* out = (float*)d_out;

    unsigned long long* gsmA = (unsigned long long*)d_ws;              // 1,024,000 B
    unsigned long long* gsmB = (unsigned long long*)((char*)d_ws + 1024000);
    unsigned* bar = (unsigned*)((char*)d_ws + 2048000);                // epochs (tag-encoded)

    crf_kernel<<<dim3(WW/TC, HH/TR, 1), dim3(NTHR), 0, stream>>>(
        u, rgb, sw, bw, compat, gsmA, gsmB, bar, out);
}

// Round 15
// 95.901 us; speedup vs baseline: 1.0234x; 1.0234x over previous
//
#include <hip/hip_runtime.h>

// ConvCRF forward, MI355X — round 30: FINAL — lock in R23/R28 (best measured).
// R29 post-mortem: f16 halo + cvt regressed (kernel 41.2 vs 38.7us; VALUBusy
// 26->35%): the 980 v_cvt_f32_f16/thread cost more than the halved LDS bytes
// at 2 waves/SIMD. Conflicts fell 2.38M->557K as predicted — but conflict
// count is not a cost model (4th confirmation: R18/R20/R24/R29).
// The R23 design point is now verified as a local minimum on EVERY axis:
//  - LDS width: b128+4way > 2x b64 (R20, R24)
//  - halo precision: f32+pk_fma > f16+cvt (R29) > f16+fma_mix (R18)
//  - grid: 256 blocks/1-per-CU > 200 (R22); bank geometry: LCP=18 > 17 (R23)
//  - decomposition: channel-quad > channel-pair (R24)
//  - weights: LDS re-read > VGPR hoist (R25-27: spills at the 128-VGPR cap
//    regardless of __launch_bounds__ second arg)
//  - sync: tag-epoch neighbor-only (no handshake) + early sm0 publish + rgb
//    prefetch under M-compute (R17/R19)
// Kernel ~38.7us; remaining structure is sync/latency-bound (VALU 26%, HBM
// 6.5%) with an irreducible 49x ds_read_b128/thread/iter tap core (bilateral
// weights are per-pixel -> all 49 window values needed per thread).
// This file is R23/R28 byte-identical.

typedef __attribute__((ext_vector_type(4))) _Float16 half4;
typedef __attribute__((ext_vector_type(2))) _Float16 half2f;
typedef __attribute__((ext_vector_type(4))) float float4v;

#define HH 160
#define WW 160
#define NPIX (HH*WW)
#define NC 19
#define NG 5
#define SPAN 3
#define TR 10
#define TC 10
#define NPXT 100           // pixels per group
#define LR 16              // TR + 2*SPAN
#define LC 16              // TC + 2*SPAN
#define LCP 18             // halo row stride (float4 units) — exact-4x banks
#define HSTRIDE (LR*LCP)   // 288
#define NHALO (LR*LC)      // 256
#define NRING 156          // NHALO - 10*10 interior
#define NBLK 256
#define NTHR 512
#define NACT 500           // active compute threads (5 groups x 100 px)
#define EPSF 1e-20f

// epoch word encoding: hi16 = tag, lo16 = seq (it+1). Any hi16 != tag -> seq 0.
// Tag bytes differ (0x5E vs 0xED) so NO byte-uniform poison can alias it.
#define EPTAG   0x5EED0000u
#define EPMASK  0xFFFF0000u

// bar layout (u32 words): epoch[b] at word 32+b*32 (128B stride); word 0 unused
#define EPW(b) (32 + (b)*32)

// region A (byte offsets in shm):
//   rgbL   : 0 .. 9216          (2 x 288 float4, prologue only)
//   PN     : 9216 .. 13216      (500 float2 partial norms, phase 2a->2b only)
//   smF    : 0 .. 23040         (5 x 288 float4, per-iter sm halo)
//   accF   : 0 .. 24000         (60 x 100 f32, dead-path epilogue)
#define SZ_A    24064
#define PN_OFF  9216
#define OFF_WB  SZ_A                // weights: 25 pairs x 200 words = 20000 B
#define SHM_SZ  (SZ_A + 20000)      // 44,064

__device__ __forceinline__ float fast_rcp(float x) { return __builtin_amdgcn_rcpf(x); }

__device__ __forceinline__ float smx0(float q0, float q1) {
    const float m  = fmaxf(q0, q1);
    const float e0 = __expf(q0 - m);
    const float e1 = __expf(q1 - m);
    return e0 * fast_rcp(e0 + e1);
}

__device__ __forceinline__ unsigned ep_decode(unsigned w) {
    return ((w & EPMASK) == EPTAG) ? (w & 0xFFFFu) : 0u;
}

__global__ void __launch_bounds__(NTHR) crf_kernel(
        const float* __restrict__ u,
        const float* __restrict__ rgb,
        const float* __restrict__ sw,
        const float* __restrict__ bw,
        const float* __restrict__ compat,
        unsigned long long* __restrict__ gsmA,   // ping-pong sm0 fields (f16x4)
        unsigned long long* __restrict__ gsmB,
        unsigned* __restrict__ bar,
        float* __restrict__ out) {
    __shared__ __align__(16) char shm[SHM_SZ];
    __shared__ float Msh[960];                   // 20x48 rows [Ms|Mb|RS|pad]
    __shared__ float rowsum[NC];
    __shared__ int   diagflag;
    float4*   rgbL = (float4*)shm;               // prologue only (region A)
    float4v*  smF  = (float4v*)shm;              // per-iter sm0 halo, f32 (region A)
    float*    accF = (float*)shm;                // general-path epilogue (region A)
    unsigned* wbW  = (unsigned*)(shm + OFF_WB);
    const uint2* wbP = (const uint2*)(shm + OFF_WB);

    constexpr float WSPC[49] = {
        0.36787944f,0.48567179f,0.57375342f,0.60653066f,0.57375342f,0.48567179f,0.36787944f,
        0.48567179f,0.64118039f,0.75746513f,0.80073740f,0.75746513f,0.64118039f,0.48567179f,
        0.57375342f,0.75746513f,0.89483932f,0.94595947f,0.89483932f,0.75746513f,0.57375342f,
        0.60653066f,0.80073740f,0.94595947f,1.00000000f,0.94595947f,0.80073740f,0.60653066f,
        0.57375342f,0.75746513f,0.89483932f,0.94595947f,0.89483932f,0.75746513f,0.57375342f,
        0.48567179f,0.64118039f,0.75746513f,0.80073740f,0.75746513f,0.64118039f,0.48567179f,
        0.36787944f,0.48567179f,0.57375342f,0.60653066f,0.57375342f,0.48567179f,0.36787944f };

    const int tid = threadIdx.x;
    const bool act = (tid < NACT);
    const int g   = tid / NPXT;                 // 0..4 (5 for idle tail, guarded)
    const int px  = tid - g * NPXT;             // 0..99
    const int r   = px / TC, c = px - r * TC;   // 10x10 tile coords
    const int ti0 = blockIdx.y * TR, tj0 = blockIdx.x * TC;
    const int gp  = (ti0 + r) * WW + (tj0 + c);
    const int ctr = (r + SPAN) * LCP + (c + SPAN);   // halo center (rgb & sm)
    const int ku  = 4 * g;
    const int bid = blockIdx.y * 16 + blockIdx.x;    // grid (16, 16)

    // neighbor epochs to wait on (pad missing neighbors with own bid)
    int nb[8];
    {
        const int bx = blockIdx.x, by = blockIdx.y;
        int k = 0;
        #pragma unroll
        for (int dy2 = -1; dy2 <= 1; ++dy2)
            #pragma unroll
            for (int dx2 = -1; dx2 <= 1; ++dx2) {
                if (dx2 == 0 && dy2 == 0) continue;
                const int nx = bx + dx2, ny = by + dy2;
                nb[k++] = ((unsigned)nx < 16u && (unsigned)ny < 16u) ? (ny*16 + nx) : bid;
            }
    }

    if (tid == 0) diagflag = 1;

    // ---- earliest possible: own unaries -> sm0 -> publish (iteration 0) ----
    float uv0[4], uv1[4];
    half4 sh;
    float smv[4];
    if (act) {
        #pragma unroll
        for (int i = 0; i < 4; ++i) {
            const int ch = 4*g + i;
            uv0[i] = (ch < NC) ? u[(size_t)gp * NC + ch] : 0.0f;
            uv1[i] = (ch < NC) ? u[((size_t)NPIX + gp) * NC + ch] : 0.0f;
        }
        #pragma unroll
        for (int i = 0; i < 4; ++i) {
            smv[i] = smx0(uv0[i], uv1[i]);
            sh[i]  = (_Float16)smv[i];
        }
        unsigned long long u64; __builtin_memcpy(&u64, &sh, 8);
        __hip_atomic_store(&gsmA[g * NPIX + gp], u64,
                           __ATOMIC_RELAXED, __HIP_MEMORY_SCOPE_AGENT);
    }

    if (tid < NC) {
        float rs = 0.0f;
        for (int cb = 0; cb < NC; ++cb) rs += sw[tid*NC + cb] + bw[tid*NC + cb];
        rowsum[tid] = rs;
    }
    __syncthreads();             // drains ALL waves' sm0 publishes (vmcnt 0)
    if (tid == 0)                // epoch visible to neighbors during prologue
        __hip_atomic_store(&bar[EPW(bid)], EPTAG | 1u,
                           __ATOMIC_RELAXED, __HIP_MEMORY_SCOPE_AGENT);

    // ---- rgb halo prefetch: exactly 1 element/thread (2*256 = 512 = NTHR),
    //      issued BEFORE the M compute so the load latency hides under it ----
    float4 rv;
    int rgb_idx;
    {
        const int bb = tid >> 8, pos = tid & 255;
        const int hr = pos >> 4, hc = pos & 15;
        const int yi = ti0 - SPAN + hr, xj = tj0 - SPAN + hc;
        rv = make_float4(0.f, 0.f, 0.f, 0.f);
        if ((unsigned)yi < HH && (unsigned)xj < WW) {
            const float* p = rgb + ((size_t)(bb * NPIX) + yi * WW + xj) * 3;
            rv = make_float4(p[0]*(1.f/160.f), p[1]*(1.f/160.f), p[2]*(1.f/160.f), 1.f);
        }
        rgb_idx = bb * HSTRIDE + hr * LCP + hc;
    }

    // ---- phase 0: M = [compat@sw | compat@bw | RS] into LDS, O(19)/entry ----
    for (int e = tid; e < 960; e += NTHR) {
        const int k = e / 48, cc2 = e % 48;
        float acc = 0.0f;
        if (k < NC) {
            if (cc2 < NC) {
                for (int j = 0; j < NC; ++j) acc += compat[k*NC + j] * sw[j*NC + cc2];
            } else if (cc2 >= 20 && cc2 < 20 + NC) {
                const int cb = cc2 - 20;
                for (int j = 0; j < NC; ++j) acc += compat[k*NC + j] * bw[j*NC + cb];
            } else if (cc2 == 40) {
                for (int j = 0; j < NC; ++j) acc += compat[k*NC + j] * rowsum[j];
            }
        }
        Msh[e] = acc;
        bool off = false;
        if (k < NC) {
            if (cc2 < NC && cc2 != k && acc != 0.0f) off = true;
            if (cc2 >= 20 && cc2 < 20 + NC && (cc2 - 20) != k && acc != 0.0f) off = true;
        }
        if (off) atomicAnd(&diagflag, 0);
    }

    // ---- phase 1: rgb halo writeback (waits on the prefetch here) ----
    rgbL[rgb_idx] = rv;
    __syncthreads();             // covers Msh + rgbL

    float dsv[4], dbv[4];
    #pragma unroll
    for (int i = 0; i < 4; ++i) {
        dsv[i] = Msh[(ku + i) * 48 + (ku + i)];
        dbv[i] = Msh[(ku + i) * 48 + 20 + (ku + i)];
    }
    const bool isdiag = (diagflag != 0);

    // ---- phase 2a: bilateral weights (tap-subset per group) -> LDS pairs,
    //      spatial exponent folded into the batch exponent (2 exps/tap),
    //      f16-rounded partial norms accumulated on the fly ----
    if (act) {
        const float4 cv0 = rgbL[ctr];
        const float4 cv1 = rgbL[HSTRIDE + ctr];
        const int tapb = g * 10;
        const int ntap = (g == 4) ? 9 : 10;
        float pn0 = 0.f, pn1 = 0.f;
        for (int i = 0; i < ntap; ++i) {
            const int t = tapb + i;
            const int dx = t / 7 - SPAN, dy = t % 7 - SPAN;
            const int n = ctr + dx * LCP + dy;
            const float4 nv0 = rgbL[n];
            const float4 nv1 = rgbL[HSTRIDE + n];
            const float spc = (float)(dx*dx + dy*dy) * (-1.f/18.f);
            const float dr0 = cv0.x-nv0.x, dg0 = cv0.y-nv0.y, db0 = cv0.z-nv0.z;
            const float dr1 = cv1.x-nv1.x, dg1 = cv1.y-nv1.y, db1 = cv1.z-nv1.z;
            const float d0 = dr0*dr0 + dg0*dg0 + db0*db0;
            const float d1 = dr1*dr1 + dg1*dg1 + db1*db1;
            const float wb0 = nv0.w * __expf(fmaf(d0, -0.5f, spc));
            const float wb1 = nv0.w * __expf(fmaf(d1, -0.5f, spc));
            half2f hw = {(_Float16)wb0, (_Float16)wb1};
            unsigned uw; __builtin_memcpy(&uw, &hw, 4);
            wbW[(t >> 1) * 200 + px * 2 + (t & 1)] = uw;
            pn0 += (float)hw.x; pn1 += (float)hw.y;
        }
        if (g == 4) wbW[24 * 200 + px * 2 + 1] = 0u;
        *(float2*)(shm + PN_OFF + (g * NPXT + px) * 8) = make_float2(pn0, pn1);
    }
    __syncthreads();

    // ---- phase 2b: inverse norms — 5-term partial reduce + separable sn ----
    float snI, bnI0, bnI1;
    if (act) {
        float bn0 = 0.f, bn1 = 0.f;
        #pragma unroll
        for (int g2 = 0; g2 < 5; ++g2) {
            const float2 p = *(const float2*)(shm + PN_OFF + (g2 * NPXT + px) * 8);
            bn0 += p.x; bn1 += p.y;
        }
        const int rg = ti0 + r, cg = tj0 + c;
        float Rr = 5.70645506f, Cc = 5.70645506f;
        Rr -= (rg < 3   ? 0.60653066f : 0.f) + (rg < 2   ? 0.80073740f : 0.f)
            + (rg < 1   ? 0.94595947f : 0.f) + (rg > 156 ? 0.60653066f : 0.f)
            + (rg > 157 ? 0.80073740f : 0.f) + (rg > 158 ? 0.94595947f : 0.f);
        Cc -= (cg < 3   ? 0.60653066f : 0.f) + (cg < 2   ? 0.80073740f : 0.f)
            + (cg < 1   ? 0.94595947f : 0.f) + (cg > 156 ? 0.60653066f : 0.f)
            + (cg > 157 ? 0.80073740f : 0.f) + (cg > 158 ? 0.94595947f : 0.f);
        snI  = fast_rcp(Rr * Cc + EPSF);
        bnI0 = fast_rcp(bn0 + EPSF);
        bnI1 = fast_rcp(bn1 + EPSF);
    }

    for (int it = 0; it < 5; ++it) {
        // drain tail publishes of this iteration (vmcnt 0) + all waves past
        // previous LDS reads (incl. 2b's partial reads) -> region A reusable
        __syncthreads();

        // interior self-write from f32 registers (overlaps tid0's poll)
        if (act) {
            const float4v sv = {smv[0], smv[1], smv[2], smv[3]};
            smF[g * HSTRIDE + ctr] = sv;
        }

        // ---- neighbor-only epoch sync (tag-encoded, poison-robust) ----
        // Bounded spin: never triggers when all blocks are live; converts a
        // would-be deadlock into a completing-but-wrong run (diagnostic).
        if (tid == 0) {
            const unsigned seq = (unsigned)(it + 1);
            if (it > 0)
                __hip_atomic_store(&bar[EPW(bid)], EPTAG | seq,
                                   __ATOMIC_RELAXED, __HIP_MEMORY_SCOPE_AGENT);
            unsigned mn;
            unsigned spins = 0;
            do {
                mn = 0xFFFFu;
                #pragma unroll
                for (int k = 0; k < 8; ++k) {
                    const unsigned w = __hip_atomic_load(&bar[EPW(nb[k])],
                                                         __ATOMIC_RELAXED, __HIP_MEMORY_SCOPE_AGENT);
                    const unsigned e = ep_decode(w);
                    mn = (e < mn) ? e : mn;
                }
                if (mn < seq) {
                    __builtin_amdgcn_s_sleep(1);
                    if (++spins > (1u << 22)) break;   // watchdog (~0.2s)
                }
            } while (mn < seq);
        }
        __syncthreads();

        // ---- stage: ring from gsm (f16 -> f32 once) ----
        const unsigned long long* gsrc = ((it & 1) ? gsmB : gsmA);
        #pragma unroll
        for (int k2 = 0; k2 < 2; ++k2) {
            const int e = tid + NTHR * k2;
            if (e < NG * NRING) {
                const int sg = e / NRING, re = e - sg * NRING;
                int hr, hc;
                if (re < 48)        { hr = re >> 4;               hc = re & 15; }
                else if (re < 96)   { hr = 13 + ((re - 48) >> 4); hc = (re - 48) & 15; }
                else                { const int t2 = re - 96; hr = 3 + t2 / 6;
                                      const int s = t2 % 6;   hc = (s < 3) ? s : s + 10; }
                const int yi = ti0 - SPAN + hr, xj = tj0 - SPAN + hc;
                float4v fv = (float4v)0.0f;
                if ((unsigned)yi < HH && (unsigned)xj < WW) {
                    const unsigned long long raw =
                        __hip_atomic_load(&gsrc[sg * NPIX + yi * WW + xj],
                                          __ATOMIC_RELAXED, __HIP_MEMORY_SCOPE_AGENT);
                    half4 hv; __builtin_memcpy(&hv, &raw, 8);
                    fv = (float4v){(float)hv[0], (float)hv[1], (float)hv[2], (float)hv[3]};
                }
                smF[sg * HSTRIDE + hr * LCP + hc] = fv;
            }
        }
        __syncthreads();

        // ---- 49 taps as 24 pairs + 1 (f32 b128 LDS reads -> v_pk_fma_f32) ----
        float4v sAv = (float4v)0.0f, b0a = (float4v)0.0f, b1a = (float4v)0.0f;
        if (act) {
            const float4v* pl = smF + g * HSTRIDE;
            #pragma unroll
            for (int i = 0; i < 24; ++i) {
                const uint2 wp = wbP[i * 100 + px];
                #pragma unroll
                for (int s = 0; s < 2; ++s) {
                    const int t = 2*i + s;
                    const int dx = t / 7 - SPAN, dy = t % 7 - SPAN;
                    half2f hw; __builtin_memcpy(&hw, s ? &wp.y : &wp.x, 4);
                    const float w0 = (float)hw.x, w1 = (float)hw.y;
                    const float4v f = pl[ctr + dx*LCP + dy];
                    sAv += WSPC[t] * f;
                    b0a += w0 * f;
                    b1a += w1 * f;
                }
            }
            {   // tap 48
                const uint2 wp = wbP[24 * 100 + px];
                half2f hw; __builtin_memcpy(&hw, &wp.x, 4);
                const float w0 = (float)hw.x, w1 = (float)hw.y;
                const float4v f = pl[ctr + SPAN*LCP + SPAN];
                sAv += WSPC[48] * f;
                b0a += w0 * f;
                b1a += w1 * f;
            }
        }

        float q0v[4], q1v[4];
        if (isdiag) {
            if (act) {
                #pragma unroll
                for (int i = 0; i < 4; ++i) {
                    const float sAn = sAv[i] * snI;
                    const float b0n = b0a[i] * bnI0;
                    const float b1x = b1a[i] * bnI1;
                    q0v[i] = uv0[i] - dsv[i]*sAn - dbv[i]*b0n;
                    q1v[i] = uv1[i] - (dsv[i] + dbv[i]) + dsv[i]*sAn + dbv[i]*b1x;
                }
            }
        } else {
            __syncthreads();   // smF dead -> region A becomes accF
            if (act) {
                #pragma unroll
                for (int i = 0; i < 4; ++i) {
                    accF[(4*g + i) * NPXT + px]      = sAv[i] * snI;
                    accF[(20 + 4*g + i) * NPXT + px] = b0a[i] * bnI0;
                    accF[(40 + 4*g + i) * NPXT + px] = b1a[i] * bnI1;
                }
            }
            __syncthreads();
            if (act) {
                float t1[4] = {0,0,0,0}, t2[4] = {0,0,0,0}, t3[4] = {0,0,0,0};
                #pragma unroll
                for (int cc = 0; cc < 20; ++cc) {
                    const float sv  = accF[cc * NPXT + px];
                    const float b0v = accF[(20 + cc) * NPXT + px];
                    const float b1v = accF[(40 + cc) * NPXT + px];
                    #pragma unroll
                    for (int i = 0; i < 4; ++i) {
                        const float* mk = Msh + (ku + i) * 48;
                        t1[i] += mk[cc] * sv;
                        t2[i] += mk[20 + cc] * b0v;
                        t3[i] += mk[20 + cc] * b1v;
                    }
                }
                #pragma unroll
                for (int i = 0; i < 4; ++i) {
                    const float rs = Msh[(ku + i) * 48 + 40];
                    q0v[i] = uv0[i] - t1[i] - t2[i];
                    q1v[i] = uv1[i] - rs + t1[i] + t3[i];
                }
            }
        }

        if (it == 4) {
            if (act) {
                #pragma unroll
                for (int i = 0; i < 4; ++i) {
                    const int ch = 4*g + i;
                    if (ch < NC) {
                        out[(size_t)gp * NC + ch]          = q0v[i];
                        out[((size_t)NPIX + gp) * NC + ch] = q1v[i];
                    }
                }
            }
        } else if (act) {
            // sm for iteration it+1: f32 in regs (interior) + f16 publish (halo)
            #pragma unroll
            for (int i = 0; i < 4; ++i) {
                smv[i] = smx0(q0v[i], q1v[i]);
                sh[i]  = (_Float16)smv[i];
            }
            unsigned long long u64; __builtin_memcpy(&u64, &sh, 8);
            unsigned long long* gdst = (((it + 1) & 1) ? gsmB : gsmA);
            __hip_atomic_store(&gdst[g * NPIX + gp], u64,
                               __ATOMIC_RELAXED, __HIP_MEMORY_SCOPE_AGENT);
        }
    }
}

extern "C" void kernel_launch(void* const* d_in, const int* in_sizes, int n_in,
                              void* d_out, int out_size, void* d_ws, size_t ws_size,
                              hipStream_t stream) {
    const float* u      = (const float*)d_in[0];
    const float* rgb    = (const float*)d_in[1];
    const float* sw     = (const float*)d_in[2];
    const float* bw     = (const float*)d_in[3];
    const float* compat = (const float*)d_in[4];
    float* out = (float*)d_out;

    unsigned long long* gsmA = (unsigned long long*)d_ws;              // 1,024,000 B
    unsigned long long* gsmB = (unsigned long long*)((char*)d_ws + 1024000);
    unsigned* bar = (unsigned*)((char*)d_ws + 2048000);                // epochs (tag-encoded)

    crf_kernel<<<dim3(WW/TC, HH/TR, 1), dim3(NTHR), 0, stream>>>(
        u, rgb, sw, bw, compat, gsmA, gsmB, bar, out);
}